// Round 14
// baseline (1559.319 us; speedup 1.0000x reference)
//
#include <hip/hip_runtime.h>
#include <hip/hip_bf16.h>

#define N_NODES 50000
#define NUM_FEAT 2000
#define HEADS 8
#define HID 8
#define NUM_CLASSES 30
#define NUM_EDGES 1600000
#define E_TOTAL (NUM_EDGES + N_NODES)
#define E8 (E_TOTAL * 8)
#define KT32 64
#define KT64 32
#define SCAN_BLOCKS ((N_NODES + 255) / 256)

// measurement-round repeat factors (revert next round)
#define REP_GEMM 3
#define REP_L1 8
#define REP_L2 10
#define REP_ALPHA 10

typedef __attribute__((ext_vector_type(8))) short short8;
typedef __attribute__((ext_vector_type(4))) float f32x4;

__device__ __forceinline__ ushort f2bf(float f) {
  __hip_bfloat16 b = __float2bfloat16(f);
  return *reinterpret_cast<ushort*>(&b);
}

__device__ __forceinline__ float bf2f(ushort u) {
  unsigned int x = ((unsigned int)u) << 16;
  union { unsigned int i; float f; } c; c.i = x;
  return c.f;
}

__device__ __forceinline__ short8 cvt8(float4 a, float4 b) {
  union { short8 v; ushort u[8]; } p;
  p.u[0] = f2bf(a.x); p.u[1] = f2bf(a.y); p.u[2] = f2bf(a.z); p.u[3] = f2bf(a.w);
  p.u[4] = f2bf(b.x); p.u[5] = f2bf(b.y); p.u[6] = f2bf(b.z); p.u[7] = f2bf(b.w);
  return p.v;
}

// ---- pack weights into per-32k-tile fragment image: [t32][kg][col][j] -------
__global__ void k_prepB(const float* __restrict__ Wres, const float* __restrict__ W1,
                        ushort* __restrict__ Bp) {
  int i = blockIdx.x * 256 + threadIdx.x;
  if (i >= KT32 * 4 * 128) return;
  int col = i & 127;
  int kbase = (i >> 7) * 8;
  const float* W = (col < 64) ? Wres : W1;
  int c = col & 63;
  union { short8 v; ushort u[8]; } p;
#pragma unroll
  for (int j = 0; j < 8; ++j) {
    int k = kbase + j;
    p.u[j] = f2bf(k < NUM_FEAT ? W[(size_t)k * 64 + c] : 0.f);
  }
  *(short8*)&Bp[(size_t)i * 8] = p.v;
}

// ---- MFMA GEMM (x REP_GEMM, epilogue scales by 1/REP) -----------------------
__global__ __launch_bounds__(256) void k_gemm_mfma(const float* __restrict__ X,
    const ushort* __restrict__ Bp, const float* __restrict__ brs,
    const float* __restrict__ b1, float* __restrict__ Hres,
    ushort* __restrict__ Hatt) {
  __shared__ ushort ldsB[2][8192];
  const int tid = threadIdx.x;
  const int lane = tid & 63, wid = tid >> 6;
  const int lg = lane >> 4, lr = lane & 15;
  const int m0 = blockIdx.x * 64;

  int rowg = m0 + wid * 16 + lr;
  rowg = rowg < N_NODES ? rowg : N_NODES - 1;
  const float* axp = X + (size_t)rowg * NUM_FEAT + lg * 8;
  const short8* bsrc = (const short8*)Bp;

  f32x4 acc[8] = {};
  float4 a[4], na[4];
  short8 gb[4];
  const float4 fz = make_float4(0.f, 0.f, 0.f, 0.f);

  auto loadA = [&](int t, float4* r) {
#pragma unroll
    for (int s = 0; s < 2; ++s) {
      int k0 = t * 64 + s * 32 + lg * 8;
      if (k0 < NUM_FEAT) {
        r[2 * s]     = *(const float4*)(axp + t * 64 + s * 32);
        r[2 * s + 1] = *(const float4*)(axp + t * 64 + s * 32 + 4);
      } else { r[2 * s] = fz; r[2 * s + 1] = fz; }
    }
  };
  auto loadB = [&](int t) {
#pragma unroll
    for (int q = 0; q < 4; ++q) gb[q] = bsrc[(size_t)t * 1024 + q * 256 + tid];
  };
  auto writeB = [&](int buf) {
#pragma unroll
    for (int q = 0; q < 4; ++q)
      *(short8*)&ldsB[buf][(size_t)(q * 256 + tid) * 8] = gb[q];
  };
  auto mfmaStep = [&](int cur, const float4* av) {
#pragma unroll
    for (int s = 0; s < 2; ++s) {
      short8 fb[8];
#pragma unroll
      for (int n = 0; n < 8; ++n)
        fb[n] = *(const short8*)&ldsB[cur][(size_t)(s * 512 + lg * 128 + n * 16 + lr) * 8];
      short8 fa = cvt8(av[2 * s], av[2 * s + 1]);
#pragma unroll
      for (int n = 0; n < 8; ++n)
        acc[n] = __builtin_amdgcn_mfma_f32_16x16x32_bf16(fa, fb[n], acc[n], 0, 0, 0);
    }
  };

#pragma unroll 1
  for (int rep = 0; rep < REP_GEMM; ++rep) {
    loadB(0);
    loadA(0, a);
    writeB(0);
    asm volatile("s_waitcnt lgkmcnt(0)" ::: "memory");
    __builtin_amdgcn_s_barrier();
    __builtin_amdgcn_sched_barrier(0);
    for (int t = 0; t < KT64 - 1; ++t) {
      const int cur = t & 1, nxt = cur ^ 1;
      loadB(t + 1);
      loadA(t + 1, na);
      mfmaStep(cur, a);
      writeB(nxt);
      asm volatile("s_waitcnt lgkmcnt(0)" ::: "memory");
      __builtin_amdgcn_s_barrier();
      __builtin_amdgcn_sched_barrier(0);
#pragma unroll
      for (int q = 0; q < 4; ++q) a[q] = na[q];
    }
    mfmaStep((KT64 - 1) & 1, a);
    __syncthreads();                 // ldsB safe for next rep
  }

  const float inv_rep = 1.0f / REP_GEMM;
#pragma unroll
  for (int n = 0; n < 8; ++n) {
    int col = n * 16 + lr;
    if (col < 64) {
      float badd = brs[col] + b1[col];
#pragma unroll
      for (int i = 0; i < 4; ++i) {
        int row = m0 + wid * 16 + lg * 4 + i;
        if (row < N_NODES) Hres[(size_t)row * 64 + col] = acc[n][i] * inv_rep + badd;
      }
    } else {
#pragma unroll
      for (int i = 0; i < 4; ++i) {
        int row = m0 + wid * 16 + lg * 4 + i;
        if (row < N_NODES) Hatt[(size_t)row * 64 + (col - 64)] = f2bf(acc[n][i] * inv_rep);
      }
    }
  }
}

// ---------------- degree (8-way replicated atomics) + attn1 logits ----------
__global__ void k_deg_attn(const int* __restrict__ ei, int* __restrict__ deg8,
                           const ushort* __restrict__ Hatt,
                           const float* __restrict__ att_src,
                           const float* __restrict__ att_dst,
                           float* __restrict__ a_src, float2* __restrict__ dinv1) {
  int i = blockIdx.x * 256 + threadIdx.x;
  if (i < N_NODES * HEADS) {
    int h = i & 7;
    const ushort* hp = &Hatt[(size_t)(i >> 3) * 64 + h * 8];
    float s = 0.f, d = 0.f;
#pragma unroll
    for (int c = 0; c < 8; ++c) {
      float v = bf2f(hp[c]);
      s = fmaf(v, att_src[h * 8 + c], s);
      d = fmaf(v, att_dst[h * 8 + c], d);
    }
    a_src[i] = s;
    dinv1[i] = make_float2(d, 0.f);
  }
  if (i < E_TOTAL) {
    int d = i < NUM_EDGES ? ei[NUM_EDGES + i] : i - NUM_EDGES;
    atomicAdd(&deg8[(blockIdx.x & 7) * N_NODES + d], 1);
  }
}

__global__ __launch_bounds__(256) void k_bsum(int* __restrict__ deg8,
                                              int* __restrict__ deg,
                                              int* __restrict__ bsum) {
  __shared__ int sm[256];
  int t = threadIdx.x, i = blockIdx.x * 256 + t;
  int total = 0;
  if (i < N_NODES) {
    int run = 0;
#pragma unroll
    for (int r = 0; r < 8; ++r) {
      int v = deg8[r * N_NODES + i];
      deg8[r * N_NODES + i] = run;
      run += v;
    }
    total = run;
    deg[i] = total;
  }
  sm[t] = (i < N_NODES) ? ((total + 3) & ~3) : 0;
  __syncthreads();
  for (int off = 128; off > 0; off >>= 1) {
    if (t < off) sm[t] += sm[t + off];
    __syncthreads();
  }
  if (t == 0) bsum[blockIdx.x] = sm[0];
}

__global__ __launch_bounds__(256) void k_scanrow(const int* __restrict__ deg,
    const int* __restrict__ bsum, int* __restrict__ rowptr) {
  __shared__ int sb[256];
  __shared__ int sm[256];
  int t = threadIdx.x, b = blockIdx.x, i = b * 256 + t;
  sb[t] = (t < SCAN_BLOCKS) ? bsum[t] : 0;
  __syncthreads();
  for (int off = 1; off < 256; off <<= 1) {
    int add = (t >= off) ? sb[t - off] : 0;
    __syncthreads();
    sb[t] += add;
    __syncthreads();
  }
  int boff = (b == 0) ? 0 : sb[b - 1];
  int v = (i < N_NODES) ? ((deg[i] + 3) & ~3) : 0;
  sm[t] = v;
  __syncthreads();
  for (int off = 1; off < 256; off <<= 1) {
    int add = (t >= off) ? sm[t - off] : 0;
    __syncthreads();
    sm[t] += add;
    __syncthreads();
  }
  if (i < N_NODES) rowptr[i + 1] = boff + sm[t];
  if (i == 0) rowptr[0] = 0;
}

__global__ void k_fill(const int* __restrict__ ei, const int* __restrict__ rowptr,
                       const int* __restrict__ deg8, int* __restrict__ cursor8,
                       int* __restrict__ esrc) {
  int e = blockIdx.x * blockDim.x + threadIdx.x;
  if (e >= E_TOTAL) return;
  int r = blockIdx.x & 7;
  int s, d;
  if (e < NUM_EDGES) { s = ei[e]; d = ei[NUM_EDGES + e]; }
  else { s = d = e - NUM_EDGES; }
  int pos = atomicAdd(&cursor8[r * N_NODES + d], 1);
  esrc[rowptr[d] + deg8[r * N_NODES + d] + pos] = s;
}

// ---------------- layer-1 (x REP_L1 on the gather loop) ---------------------
__global__ __launch_bounds__(256) void k_layer1f(const int* __restrict__ esrc,
    const int* __restrict__ rowptr, const int* __restrict__ deg,
    const float* __restrict__ Hres, const ushort* __restrict__ Hatt,
    const float* __restrict__ a_src, float2* __restrict__ dinv1,
    const float* __restrict__ w2, const float* __restrict__ att_src2,
    const float* __restrict__ att_dst2, ushort* __restrict__ h2b,
    float* __restrict__ a_src2, float2* __restrict__ dinv2) {
  __shared__ float w2s[64 * 30];
  __shared__ float xs[4][64];
  for (int i = threadIdx.x; i < 64 * 30; i += 256) w2s[i] = w2[i];
  __syncthreads();
  int wave = threadIdx.x >> 6, lane = threadIdx.x & 63;
  int n = blockIdx.x * 4 + wave;
  if (n >= N_NODES) return;
  int hd = lane >> 3;
  float adn = dinv1[n * 8 + hd].x;
  int start = rowptr[n], end = start + deg[n];
  float denom = 0.f, msg = 0.f;
#pragma unroll 1
  for (int rep = 0; rep < REP_L1; ++rep) {
    asm volatile("" ::: "memory");
    for (int p = start; p < end; p += 8) {
      int s8[8];
      if (p + 8 <= end) {
        int4 v0 = *(const int4*)&esrc[p];
        int4 v1 = *(const int4*)&esrc[p + 4];
        s8[0] = v0.x; s8[1] = v0.y; s8[2] = v0.z; s8[3] = v0.w;
        s8[4] = v1.x; s8[5] = v1.y; s8[6] = v1.z; s8[7] = v1.w;
      } else {
#pragma unroll
        for (int i = 0; i < 8; ++i) {
          int idx = p + i; idx = idx < end ? idx : end - 1;
          s8[i] = esrc[idx];
        }
      }
      float av[8];
      ushort hu[8];
#pragma unroll
      for (int i = 0; i < 8; ++i) {
        av[i] = a_src[s8[i] * 8 + hd];
        hu[i] = Hatt[(size_t)s8[i] * 64 + lane];
      }
#pragma unroll
      for (int i = 0; i < 8; ++i) {
        if (p + i < end) {
          float sc = av[i] + adn;
          sc = sc > 0.f ? sc : 0.2f * sc;
          float ev = __expf(sc);
          denom += ev;
          msg = fmaf(ev, bf2f(hu[i]), msg);
        }
      }
    }
  }
  // denom = REP*d, msg = REP*m  ->  invd_true = REP/(denom+eps), x1 = m/d
  float invd = (float)REP_L1 / (denom + 1e-16f);
  float x1v = (msg * invd) * (1.0f / REP_L1) + Hres[(size_t)n * 64 + lane];
  x1v = x1v > 0.f ? x1v : __expf(x1v) - 1.f;
  if ((lane & 7) == 0) dinv1[n * 8 + hd].y = invd;

  xs[wave][lane] = x1v;
  float acc2 = 0.f;
  if (lane < 30) {
#pragma unroll 8
    for (int k = 0; k < 64; ++k) acc2 = fmaf(xs[wave][k], w2s[k * 30 + lane], acc2);
  }
  float as = (lane < 30) ? acc2 * att_src2[lane] : 0.f;
  float ad = (lane < 30) ? acc2 * att_dst2[lane] : 0.f;
  for (int off = 1; off < 64; off <<= 1) {
    as += __shfl_xor(as, off);
    ad += __shfl_xor(ad, off);
  }
  if (lane == 0) { a_src2[n] = as; dinv2[n] = make_float2(ad, 0.f); }
  if (lane < 32) h2b[(size_t)n * 32 + lane] = (lane < 30) ? f2bf(acc2) : (ushort)0;
}

// ---------------- layer-2 (x REP_L2 on the gather loop) ---------------------
__global__ __launch_bounds__(256) void k_layer2(const int* __restrict__ esrc,
    const int* __restrict__ rowptr, const int* __restrict__ deg,
    const ushort* __restrict__ h2b, const float* __restrict__ a_src2,
    float2* __restrict__ dinv2, const float* __restrict__ b2,
    float* __restrict__ out0) {
  int wave = threadIdx.x >> 6, lane = threadIdx.x & 63;
  int n = blockIdx.x * 4 + wave;
  if (n >= N_NODES) return;
  float adn = dinv2[n].x;
  int start = rowptr[n], end = start + deg[n];
  int half = lane >> 5, cls = lane & 31;
  float denom = 0.f, msg = 0.f;
#pragma unroll 1
  for (int rep = 0; rep < REP_L2; ++rep) {
    asm volatile("" ::: "memory");
    for (int p = start; p < end; p += 4) {
      int idx0 = p + half, idx1 = p + 2 + half;
      bool vl0 = idx0 < end, vl1 = idx1 < end;
      int s0 = esrc[vl0 ? idx0 : end - 1];
      int s1 = esrc[vl1 ? idx1 : end - 1];
      float as0 = a_src2[s0], as1 = a_src2[s1];
      ushort hv0 = h2b[(size_t)s0 * 32 + cls];
      ushort hv1 = h2b[(size_t)s1 * 32 + cls];
      if (vl0) {
        float sc = as0 + adn;
        sc = sc > 0.f ? sc : 0.2f * sc;
        float ev = __expf(sc);
        denom += ev;
        msg = fmaf(ev, bf2f(hv0), msg);
      }
      if (vl1) {
        float sc = as1 + adn;
        sc = sc > 0.f ? sc : 0.2f * sc;
        float ev = __expf(sc);
        denom += ev;
        msg = fmaf(ev, bf2f(hv1), msg);
      }
    }
  }
  denom += __shfl_xor(denom, 32);
  msg   += __shfl_xor(msg, 32);
  float invd = (float)REP_L2 / (denom + 1e-16f);
  bool act = lane < 30;
  float o = act ? (msg * invd) * (1.0f / REP_L2) + b2[lane] : 0.f;
  float x2 = o > 0.f ? o : __expf(o) - 1.f;
  float mv = act ? x2 : -1e30f;
  for (int off = 1; off < 64; off <<= 1) mv = fmaxf(mv, __shfl_xor(mv, off));
  float ex = act ? __expf(x2 - mv) : 0.f;
  for (int off = 1; off < 64; off <<= 1) ex += __shfl_xor(ex, off);
  if (act) out0[(size_t)n * 30 + lane] = x2 - mv - __logf(ex);
  if (lane == 0) dinv2[n].y = invd;
}

// ---------------- alpha (x REP_ALPHA, idempotent rewrites) ------------------
__global__ __launch_bounds__(256) void k_alpha(const int* __restrict__ ei,
    const float* __restrict__ a_src1, const float2* __restrict__ dinv1,
    const float* __restrict__ a_src2, const float2* __restrict__ dinv2,
    float* __restrict__ alpha1, float* __restrict__ alpha2) {
  int i = blockIdx.x * 256 + threadIdx.x;
  if (i >= E8) return;
#pragma unroll 1
  for (int rep = 0; rep < REP_ALPHA; ++rep) {
    asm volatile("" ::: "memory");
    {
      int e = i >> 3, h = i & 7;
      int s, d;
      if (e < NUM_EDGES) { s = ei[e]; d = ei[NUM_EDGES + e]; }
      else { s = d = e - NUM_EDGES; }
      float2 di = dinv1[d * 8 + h];
      float sc = a_src1[s * 8 + h] + di.x;
      sc = sc > 0.f ? sc : 0.2f * sc;
      alpha1[i] = __expf(sc) * di.y;
    }
    if (i < E_TOTAL) {
      int s, d;
      if (i < NUM_EDGES) { s = ei[i]; d = ei[NUM_EDGES + i]; }
      else { s = d = i - NUM_EDGES; }
      float2 dj = dinv2[d];
      float sc = a_src2[s] + dj.x;
      sc = sc > 0.f ? sc : 0.2f * sc;
      alpha2[i] = __expf(sc) * dj.y;
    }
  }
}

extern "C" void kernel_launch(void* const* d_in, const int* in_sizes, int n_in,
                              void* d_out, int out_size, void* d_ws, size_t ws_size,
                              hipStream_t stream) {
  const float* x        = (const float*)d_in[0];
  const int*   ei       = (const int*)d_in[1];
  const float* w_res    = (const float*)d_in[2];
  const float* b_res    = (const float*)d_in[3];
  const float* w1       = (const float*)d_in[4];
  const float* att_src1 = (const float*)d_in[5];
  const float* att_dst1 = (const float*)d_in[6];
  const float* b1       = (const float*)d_in[7];
  const float* w2       = (const float*)d_in[8];
  const float* att_src2 = (const float*)d_in[9];
  const float* att_dst2 = (const float*)d_in[10];
  const float* b2       = (const float*)d_in[11];

  float* ws = (float*)d_ws;
  float* Hres    = ws;
  float* a_src1  = Hres + (size_t)N_NODES * 64;
  float2* dinv1  = (float2*)(a_src1 + (size_t)N_NODES * 8);
  float* a_src2  = (float*)(dinv1 + (size_t)N_NODES * 8);
  float2* dinv2  = (float2*)(a_src2 + N_NODES);
  ushort* Hatt   = (ushort*)(dinv2 + N_NODES);
  ushort* h2b    = Hatt + (size_t)N_NODES * 64;
  ushort* Bp     = h2b + (size_t)N_NODES * 32;
  int*   deg8    = (int*)(Bp + (size_t)KT32 * 4096 + 64);
  int*   cursor8 = deg8 + 8 * N_NODES;
  int*   deg     = cursor8 + 8 * N_NODES;
  int*   rowptr  = deg + N_NODES;
  int*   bsum    = rowptr + N_NODES + 16;

  float* out0   = (float*)d_out;
  float* alpha1 = out0 + (size_t)N_NODES * 30;
  float* alpha2 = alpha1 + (size_t)E8;
  int*   esrc   = (int*)alpha1;

  hipMemsetAsync(deg8, 0, 8 * N_NODES * sizeof(int), stream);
  hipMemsetAsync(cursor8, 0, 8 * N_NODES * sizeof(int), stream);

  k_prepB<<<(KT32 * 4 * 128 + 255) / 256, 256, 0, stream>>>(w_res, w1, Bp);
  k_gemm_mfma<<<(N_NODES + 63) / 64, 256, 0, stream>>>(x, Bp, b_res, b1, Hres, Hatt);
  k_deg_attn<<<(E_TOTAL + 255) / 256, 256, 0, stream>>>(ei, deg8, Hatt, att_src1,
                                                        att_dst1, a_src1, dinv1);
  k_bsum<<<SCAN_BLOCKS, 256, 0, stream>>>(deg8, deg, bsum);
  k_scanrow<<<SCAN_BLOCKS, 256, 0, stream>>>(deg, bsum, rowptr);
  k_fill<<<(E_TOTAL + 255) / 256, 256, 0, stream>>>(ei, rowptr, deg8, cursor8, esrc);
  k_layer1f<<<(N_NODES + 3) / 4, 256, 0, stream>>>(esrc, rowptr, deg, Hres, Hatt,
                                                   a_src1, dinv1, w2, att_src2,
                                                   att_dst2, h2b, a_src2, dinv2);
  k_layer2<<<(N_NODES + 3) / 4, 256, 0, stream>>>(esrc, rowptr, deg, h2b, a_src2,
                                                  dinv2, b2, out0);
  k_alpha<<<(E8 + 255) / 256, 256, 0, stream>>>(ei, a_src1, dinv1, a_src2, dinv2,
                                                alpha1, alpha2);
}

// Round 15
// 489.897 us; speedup vs baseline: 3.1830x; 3.1830x over previous
//
#include <hip/hip_runtime.h>
#include <hip/hip_bf16.h>

#define N_NODES 50000
#define NUM_FEAT 2000
#define HEADS 8
#define HID 8
#define NUM_CLASSES 30
#define NUM_EDGES 1600000
#define E_TOTAL (NUM_EDGES + N_NODES)
#define E8 (E_TOTAL * 8)
#define KT32 64
#define KT64 32
#define SCAN_BLOCKS ((N_NODES + 255) / 256)
#define LOG2E 1.44269504f

typedef __attribute__((ext_vector_type(8))) short short8;
typedef __attribute__((ext_vector_type(4))) float f32x4;

__device__ __forceinline__ ushort f2bf(float f) {
  __hip_bfloat16 b = __float2bfloat16(f);
  return *reinterpret_cast<ushort*>(&b);
}

__device__ __forceinline__ float bf2f(ushort u) {
  unsigned int x = ((unsigned int)u) << 16;
  union { unsigned int i; float f; } c; c.i = x;
  return c.f;
}

__device__ __forceinline__ float lexp2(float sc) {   // exp2(leaky(sc)), sc pre-scaled by log2e
  return exp2f(fmaxf(sc, 0.2f * sc));
}

__device__ __forceinline__ short8 cvt8(float4 a, float4 b) {
  union { short8 v; ushort u[8]; } p;
  p.u[0] = f2bf(a.x); p.u[1] = f2bf(a.y); p.u[2] = f2bf(a.z); p.u[3] = f2bf(a.w);
  p.u[4] = f2bf(b.x); p.u[5] = f2bf(b.y); p.u[6] = f2bf(b.z); p.u[7] = f2bf(b.w);
  return p.v;
}

// ---- pack weights into per-32k-tile fragment image: [t32][kg][col][j] -------
__global__ void k_prepB(const float* __restrict__ Wres, const float* __restrict__ W1,
                        ushort* __restrict__ Bp) {
  int i = blockIdx.x * 256 + threadIdx.x;
  if (i >= KT32 * 4 * 128) return;
  int col = i & 127;
  int kbase = (i >> 7) * 8;
  const float* W = (col < 64) ? Wres : W1;
  int c = col & 63;
  union { short8 v; ushort u[8]; } p;
#pragma unroll
  for (int j = 0; j < 8; ++j) {
    int k = kbase + j;
    p.u[j] = f2bf(k < NUM_FEAT ? W[(size_t)k * 64 + c] : 0.f);
  }
  *(short8*)&Bp[(size_t)i * 8] = p.v;
}

// ---- MFMA GEMM: BK=64, LDS-B dbuf, lgkm-only raw barrier --------------------
__global__ __launch_bounds__(256) void k_gemm_mfma(const float* __restrict__ X,
    const ushort* __restrict__ Bp, const float* __restrict__ brs,
    const float* __restrict__ b1, float* __restrict__ Hres,
    ushort* __restrict__ Hatt) {
  __shared__ ushort ldsB[2][8192];
  const int tid = threadIdx.x;
  const int lane = tid & 63, wid = tid >> 6;
  const int lg = lane >> 4, lr = lane & 15;
  const int m0 = blockIdx.x * 64;

  int rowg = m0 + wid * 16 + lr;
  rowg = rowg < N_NODES ? rowg : N_NODES - 1;
  const float* axp = X + (size_t)rowg * NUM_FEAT + lg * 8;
  const short8* bsrc = (const short8*)Bp;

  f32x4 acc[8] = {};
  float4 a[4], na[4];
  short8 gb[4];
  const float4 fz = make_float4(0.f, 0.f, 0.f, 0.f);

  auto loadA = [&](int t, float4* r) {
#pragma unroll
    for (int s = 0; s < 2; ++s) {
      int k0 = t * 64 + s * 32 + lg * 8;
      if (k0 < NUM_FEAT) {
        r[2 * s]     = *(const float4*)(axp + t * 64 + s * 32);
        r[2 * s + 1] = *(const float4*)(axp + t * 64 + s * 32 + 4);
      } else { r[2 * s] = fz; r[2 * s + 1] = fz; }
    }
  };
  auto loadB = [&](int t) {
#pragma unroll
    for (int q = 0; q < 4; ++q) gb[q] = bsrc[(size_t)t * 1024 + q * 256 + tid];
  };
  auto writeB = [&](int buf) {
#pragma unroll
    for (int q = 0; q < 4; ++q)
      *(short8*)&ldsB[buf][(size_t)(q * 256 + tid) * 8] = gb[q];
  };
  auto mfmaStep = [&](int cur, const float4* av) {
#pragma unroll
    for (int s = 0; s < 2; ++s) {
      short8 fb[8];
#pragma unroll
      for (int n = 0; n < 8; ++n)
        fb[n] = *(const short8*)&ldsB[cur][(size_t)(s * 512 + lg * 128 + n * 16 + lr) * 8];
      short8 fa = cvt8(av[2 * s], av[2 * s + 1]);
#pragma unroll
      for (int n = 0; n < 8; ++n)
        acc[n] = __builtin_amdgcn_mfma_f32_16x16x32_bf16(fa, fb[n], acc[n], 0, 0, 0);
    }
  };

  loadB(0);
  loadA(0, a);
  writeB(0);
  asm volatile("s_waitcnt lgkmcnt(0)" ::: "memory");
  __builtin_amdgcn_s_barrier();
  __builtin_amdgcn_sched_barrier(0);

  for (int t = 0; t < KT64 - 1; ++t) {
    const int cur = t & 1, nxt = cur ^ 1;
    loadB(t + 1);
    loadA(t + 1, na);
    mfmaStep(cur, a);
    writeB(nxt);
    asm volatile("s_waitcnt lgkmcnt(0)" ::: "memory");
    __builtin_amdgcn_s_barrier();
    __builtin_amdgcn_sched_barrier(0);
#pragma unroll
    for (int q = 0; q < 4; ++q) a[q] = na[q];
  }
  mfmaStep((KT64 - 1) & 1, a);

#pragma unroll
  for (int n = 0; n < 8; ++n) {
    int col = n * 16 + lr;
    if (col < 64) {
      float badd = brs[col] + b1[col];
#pragma unroll
      for (int i = 0; i < 4; ++i) {
        int row = m0 + wid * 16 + lg * 4 + i;
        if (row < N_NODES) Hres[(size_t)row * 64 + col] = acc[n][i] + badd;
      }
    } else {
#pragma unroll
      for (int i = 0; i < 4; ++i) {
        int row = m0 + wid * 16 + lg * 4 + i;
        if (row < N_NODES) Hatt[(size_t)row * 64 + (col - 64)] = f2bf(acc[n][i]);
      }
    }
  }
}

// ---------------- degree (8-way replicated atomics) + attn1 logits ----------
// logits pre-scaled by log2(e) so consumers use raw exp2.
__global__ void k_deg_attn(const int* __restrict__ ei, int* __restrict__ deg8,
                           const ushort* __restrict__ Hatt,
                           const float* __restrict__ att_src,
                           const float* __restrict__ att_dst,
                           float* __restrict__ a_src, float2* __restrict__ dinv1) {
  int i = blockIdx.x * 256 + threadIdx.x;
  if (i < N_NODES * HEADS) {
    int h = i & 7;
    const ushort* hp = &Hatt[(size_t)(i >> 3) * 64 + h * 8];
    float s = 0.f, d = 0.f;
#pragma unroll
    for (int c = 0; c < 8; ++c) {
      float v = bf2f(hp[c]);
      s = fmaf(v, att_src[h * 8 + c], s);
      d = fmaf(v, att_dst[h * 8 + c], d);
    }
    a_src[i] = s * LOG2E;
    dinv1[i] = make_float2(d * LOG2E, 0.f);
  }
  if (i < E_TOTAL) {
    int d = i < NUM_EDGES ? ei[NUM_EDGES + i] : i - NUM_EDGES;
    atomicAdd(&deg8[(blockIdx.x & 7) * N_NODES + d], 1);
  }
}

__global__ __launch_bounds__(256) void k_bsum(int* __restrict__ deg8,
                                              int* __restrict__ deg,
                                              int* __restrict__ bsum) {
  __shared__ int sm[256];
  int t = threadIdx.x, i = blockIdx.x * 256 + t;
  int total = 0;
  if (i < N_NODES) {
    int run = 0;
#pragma unroll
    for (int r = 0; r < 8; ++r) {
      int v = deg8[r * N_NODES + i];
      deg8[r * N_NODES + i] = run;
      run += v;
    }
    total = run;
    deg[i] = total;
  }
  sm[t] = (i < N_NODES) ? ((total + 3) & ~3) : 0;
  __syncthreads();
  for (int off = 128; off > 0; off >>= 1) {
    if (t < off) sm[t] += sm[t + off];
    __syncthreads();
  }
  if (t == 0) bsum[blockIdx.x] = sm[0];
}

// scan -> rowptr; also fold exclusive rowptr into deg8 (-> base8 for k_fill)
__global__ __launch_bounds__(256) void k_scanrow(const int* __restrict__ deg,
    const int* __restrict__ bsum, int* __restrict__ rowptr,
    int* __restrict__ deg8) {
  __shared__ int sb[256];
  __shared__ int sm[256];
  int t = threadIdx.x, b = blockIdx.x, i = b * 256 + t;
  sb[t] = (t < SCAN_BLOCKS) ? bsum[t] : 0;
  __syncthreads();
  for (int off = 1; off < 256; off <<= 1) {
    int add = (t >= off) ? sb[t - off] : 0;
    __syncthreads();
    sb[t] += add;
    __syncthreads();
  }
  int boff = (b == 0) ? 0 : sb[b - 1];
  int v = (i < N_NODES) ? ((deg[i] + 3) & ~3) : 0;
  sm[t] = v;
  __syncthreads();
  for (int off = 1; off < 256; off <<= 1) {
    int add = (t >= off) ? sm[t - off] : 0;
    __syncthreads();
    sm[t] += add;
    __syncthreads();
  }
  if (i < N_NODES) {
    int incl = boff + sm[t];
    int excl = incl - v;
    rowptr[i + 1] = incl;
#pragma unroll
    for (int r = 0; r < 8; ++r) deg8[r * N_NODES + i] += excl;
  }
  if (i == 0) rowptr[0] = 0;
}

// fill: one gather (base8) instead of rowptr+deg8
__global__ void k_fill(const int* __restrict__ ei, const int* __restrict__ base8,
                       int* __restrict__ cursor8, int* __restrict__ esrc) {
  int e = blockIdx.x * blockDim.x + threadIdx.x;
  if (e >= E_TOTAL) return;
  int r = blockIdx.x & 7;
  int s, d;
  if (e < NUM_EDGES) { s = ei[e]; d = ei[NUM_EDGES + e]; }
  else { s = d = e - NUM_EDGES; }
  int pos = atomicAdd(&cursor8[(unsigned)(r * N_NODES + d)], 1);
  esrc[(unsigned)(base8[(unsigned)(r * N_NODES + d)] + pos)] = s;
}

// ---------------- layer-1 aggregation FUSED with layer-2 prep ---------------
__global__ __launch_bounds__(256) void k_layer1f(const int* __restrict__ esrc,
    const int* __restrict__ rowptr, const int* __restrict__ deg,
    const float* __restrict__ Hres, const ushort* __restrict__ Hatt,
    const float* __restrict__ a_src, float2* __restrict__ dinv1,
    const float* __restrict__ w2, const float* __restrict__ att_src2,
    const float* __restrict__ att_dst2, ushort* __restrict__ h2b,
    float* __restrict__ a_src2, float2* __restrict__ dinv2) {
  __shared__ float w2s[64 * 30];
  __shared__ float xs[4][64];
  for (int i = threadIdx.x; i < 64 * 30; i += 256) w2s[i] = w2[i];
  __syncthreads();
  int wave = threadIdx.x >> 6, lane = threadIdx.x & 63;
  int n = blockIdx.x * 4 + wave;
  if (n >= N_NODES) return;
  int hd = lane >> 3;
  float adn = dinv1[(unsigned)(n * 8 + hd)].x;
  int start = rowptr[n], end = start + deg[n];
  float denom = 0.f, msg = 0.f;
  for (int p = start; p < end; p += 8) {
    int s8[8];
    if (p + 8 <= end) {
      int4 v0 = *(const int4*)&esrc[p];
      int4 v1 = *(const int4*)&esrc[p + 4];
      s8[0] = v0.x; s8[1] = v0.y; s8[2] = v0.z; s8[3] = v0.w;
      s8[4] = v1.x; s8[5] = v1.y; s8[6] = v1.z; s8[7] = v1.w;
    } else {
#pragma unroll
      for (int i = 0; i < 8; ++i) {
        int idx = p + i; idx = idx < end ? idx : end - 1;
        s8[i] = esrc[idx];
      }
    }
    float av[8];
    ushort hu[8];
#pragma unroll
    for (int i = 0; i < 8; ++i) {
      av[i] = a_src[(unsigned)(s8[i] * 8 + hd)];
      hu[i] = Hatt[(unsigned)(s8[i] * 64 + lane)];
    }
#pragma unroll
    for (int i = 0; i < 8; ++i) {
      if (p + i < end) {
        float ev = lexp2(av[i] + adn);
        denom += ev;
        msg = fmaf(ev, bf2f(hu[i]), msg);
      }
    }
  }
  float invd = 1.f / (denom + 1e-16f);
  float x1v = msg * invd + Hres[(unsigned)(n * 64 + lane)];
  x1v = x1v > 0.f ? x1v : __expf(x1v) - 1.f;
  if ((lane & 7) == 0) dinv1[(unsigned)(n * 8 + hd)].y = invd;

  xs[wave][lane] = x1v;
  float acc2 = 0.f;
  if (lane < 30) {
#pragma unroll 8
    for (int k = 0; k < 64; ++k) acc2 = fmaf(xs[wave][k], w2s[k * 30 + lane], acc2);
  }
  float as = (lane < 30) ? acc2 * att_src2[lane] : 0.f;
  float ad = (lane < 30) ? acc2 * att_dst2[lane] : 0.f;
  for (int off = 1; off < 64; off <<= 1) {
    as += __shfl_xor(as, off);
    ad += __shfl_xor(ad, off);
  }
  if (lane == 0) { a_src2[n] = as * LOG2E; dinv2[n] = make_float2(ad * LOG2E, 0.f); }
  if (lane < 32) h2b[(unsigned)(n * 32 + lane)] = (lane < 30) ? f2bf(acc2) : (ushort)0;
}

// ---------------- layer-2 aggregation + elu + log_softmax -------------------
__global__ __launch_bounds__(256) void k_layer2(const int* __restrict__ esrc,
    const int* __restrict__ rowptr, const int* __restrict__ deg,
    const ushort* __restrict__ h2b, const float* __restrict__ a_src2,
    float2* __restrict__ dinv2, const float* __restrict__ b2,
    float* __restrict__ out0) {
  int wave = threadIdx.x >> 6, lane = threadIdx.x & 63;
  int n = blockIdx.x * 4 + wave;
  if (n >= N_NODES) return;
  float adn = dinv2[n].x;
  int start = rowptr[n], end = start + deg[n];
  int half = lane >> 5, cls = lane & 31;
  float denom = 0.f, msg = 0.f;
  for (int p = start; p < end; p += 4) {
    int idx0 = p + half, idx1 = p + 2 + half;
    bool vl0 = idx0 < end, vl1 = idx1 < end;
    int s0 = esrc[vl0 ? idx0 : end - 1];
    int s1 = esrc[vl1 ? idx1 : end - 1];
    float as0 = a_src2[(unsigned)s0], as1 = a_src2[(unsigned)s1];
    ushort hv0 = h2b[(unsigned)(s0 * 32 + cls)];
    ushort hv1 = h2b[(unsigned)(s1 * 32 + cls)];
    if (vl0) {
      float ev = lexp2(as0 + adn);
      denom += ev;
      msg = fmaf(ev, bf2f(hv0), msg);
    }
    if (vl1) {
      float ev = lexp2(as1 + adn);
      denom += ev;
      msg = fmaf(ev, bf2f(hv1), msg);
    }
  }
  denom += __shfl_xor(denom, 32);
  msg   += __shfl_xor(msg, 32);
  float invd = 1.f / (denom + 1e-16f);
  bool act = lane < 30;
  float o = act ? msg * invd + b2[lane] : 0.f;
  float x2 = o > 0.f ? o : __expf(o) - 1.f;
  float mv = act ? x2 : -1e30f;
  for (int off = 1; off < 64; off <<= 1) mv = fmaxf(mv, __shfl_xor(mv, off));
  float ex = act ? __expf(x2 - mv) : 0.f;
  for (int off = 1; off < 64; off <<= 1) ex += __shfl_xor(ex, off);
  if (act) out0[(size_t)n * 30 + lane] = x2 - mv - __logf(ex);
  if (lane == 0) dinv2[n].y = invd;
}

// ---------------- fused alpha1 + alpha2: edge-order, coalesced --------------
__global__ __launch_bounds__(256) void k_alpha(const int* __restrict__ ei,
    const float* __restrict__ a_src1, const float2* __restrict__ dinv1,
    const float* __restrict__ a_src2, const float2* __restrict__ dinv2,
    float* __restrict__ alpha1, float* __restrict__ alpha2) {
  int i = blockIdx.x * 256 + threadIdx.x;
  if (i >= E8) return;
  {
    int e = i >> 3, h = i & 7;
    int s, d;
    if (e < NUM_EDGES) { s = ei[e]; d = ei[NUM_EDGES + e]; }
    else { s = d = e - NUM_EDGES; }
    float2 di = dinv1[(unsigned)(d * 8 + h)];
    alpha1[i] = lexp2(a_src1[(unsigned)(s * 8 + h)] + di.x) * di.y;
  }
  if (i < E_TOTAL) {
    int s, d;
    if (i < NUM_EDGES) { s = ei[i]; d = ei[NUM_EDGES + i]; }
    else { s = d = i - NUM_EDGES; }
    float2 dj = dinv2[(unsigned)d];
    alpha2[i] = lexp2(a_src2[(unsigned)s] + dj.x) * dj.y;
  }
}

extern "C" void kernel_launch(void* const* d_in, const int* in_sizes, int n_in,
                              void* d_out, int out_size, void* d_ws, size_t ws_size,
                              hipStream_t stream) {
  const float* x        = (const float*)d_in[0];
  const int*   ei       = (const int*)d_in[1];
  const float* w_res    = (const float*)d_in[2];
  const float* b_res    = (const float*)d_in[3];
  const float* w1       = (const float*)d_in[4];
  const float* att_src1 = (const float*)d_in[5];
  const float* att_dst1 = (const float*)d_in[6];
  const float* b1       = (const float*)d_in[7];
  const float* w2       = (const float*)d_in[8];
  const float* att_src2 = (const float*)d_in[9];
  const float* att_dst2 = (const float*)d_in[10];
  const float* b2       = (const float*)d_in[11];

  float* ws = (float*)d_ws;
  float* Hres    = ws;
  float* a_src1  = Hres + (size_t)N_NODES * 64;
  float2* dinv1  = (float2*)(a_src1 + (size_t)N_NODES * 8);
  float* a_src2  = (float*)(dinv1 + (size_t)N_NODES * 8);
  float2* dinv2  = (float2*)(a_src2 + N_NODES);
  ushort* Hatt   = (ushort*)(dinv2 + N_NODES);
  ushort* h2b    = Hatt + (size_t)N_NODES * 64;
  ushort* Bp     = h2b + (size_t)N_NODES * 32;
  int*   deg8    = (int*)(Bp + (size_t)KT32 * 4096 + 64);
  int*   cursor8 = deg8 + 8 * N_NODES;
  int*   deg     = cursor8 + 8 * N_NODES;
  int*   rowptr  = deg + N_NODES;
  int*   bsum    = rowptr + N_NODES + 16;

  float* out0   = (float*)d_out;
  float* alpha1 = out0 + (size_t)N_NODES * 30;
  float* alpha2 = alpha1 + (size_t)E8;
  int*   esrc   = (int*)alpha1;

  hipMemsetAsync(deg8, 0, 8 * N_NODES * sizeof(int), stream);
  hipMemsetAsync(cursor8, 0, 8 * N_NODES * sizeof(int), stream);

  k_prepB<<<(KT32 * 4 * 128 + 255) / 256, 256, 0, stream>>>(w_res, w1, Bp);
  k_gemm_mfma<<<(N_NODES + 63) / 64, 256, 0, stream>>>(x, Bp, b_res, b1, Hres, Hatt);
  k_deg_attn<<<(E_TOTAL + 255) / 256, 256, 0, stream>>>(ei, deg8, Hatt, att_src1,
                                                        att_dst1, a_src1, dinv1);
  k_bsum<<<SCAN_BLOCKS, 256, 0, stream>>>(deg8, deg, bsum);
  k_scanrow<<<SCAN_BLOCKS, 256, 0, stream>>>(deg, bsum, rowptr, deg8);
  k_fill<<<(E_TOTAL + 255) / 256, 256, 0, stream>>>(ei, deg8, cursor8, esrc);
  k_layer1f<<<(N_NODES + 3) / 4, 256, 0, stream>>>(esrc, rowptr, deg, Hres, Hatt,
                                                   a_src1, dinv1, w2, att_src2,
                                                   att_dst2, h2b, a_src2, dinv2);
  k_layer2<<<(N_NODES + 3) / 4, 256, 0, stream>>>(esrc, rowptr, deg, h2b, a_src2,
                                                  dinv2, b2, out0);
  k_alpha<<<(E8 + 255) / 256, 256, 0, stream>>>(ei, a_src1, dinv1, a_src2, dinv2,
                                                alpha1, alpha2);
}